// Round 17
// baseline (1256.080 us; speedup 1.0000x reference)
//
#include <hip/hip_runtime.h>
#include <hip/hip_bf16.h>

// B=2, S=2048, W=32, D=1024, H=16, hd=64
// Pipeline (full path):
//   bf16-cast: cast4_kernel (Wq,Wk,Wv,Wo in one launch), q (cast_kernel)
//   K+V GEMM: gemm_mid = 128x128 tile (the harness-verified gemm_lds
//             structure: 256 thr / 4 waves / acc[4][4]=64 AGPR / 32KB LDS
//             -> 3-4 blocks/CU occupancy, vs the 256x256 kernel's proven
//             1-block/CU plateau at ~32% MfmaUtil over 7 schedule variants)
//             with fp32-A fused cast: reg-stage 8x float4 -> v_cvt_pk ->
//             swizzled ds_write (gemm_bias's verified write-XOR, composes
//             with gemm_lds's read-XOR); B via global_load_lds. Merged
//             K+V in one 16384-block launch; XCD-grouped so the 8
//             bn-blocks of an A-row-panel are dispatch-adjacent (A
//             re-reads absorbed by L2/L3).
//   Q/O GEMM: gemm_lds (128x128)
//   attn: per (b,s') head-softmax gather-attention -> A (4096x1024 bf16)
//   out  = A@Wo^T+bo (fp32)

#define DEVI __device__ __forceinline__

typedef __attribute__((ext_vector_type(8))) short bf16x8;
typedef __attribute__((ext_vector_type(4))) float f32x4;
typedef const __attribute__((address_space(1))) void* gvp;
typedef __attribute__((address_space(3))) void* lvp;

DEVI ushort f2bf(float f) {
  uint u = __float_as_uint(f);
  u = u + 0x7fffu + ((u >> 16) & 1u);
  return (ushort)(u >> 16);
}
DEVI float bf2f(ushort u) { return __uint_as_float(((uint)u) << 16); }

// ---------------- elementwise fp32 -> bf16 cast (RNE), 8 elems/thread ----
__global__ __launch_bounds__(256) void cast_kernel(const float* __restrict__ in,
                                                   ushort* __restrict__ out,
                                                   long n) {
  long i = ((long)blockIdx.x * 256 + threadIdx.x) * 8;
  const long stride = (long)gridDim.x * 256 * 8;
  for (; i < n; i += stride) {
    float4 a = *reinterpret_cast<const float4*>(in + i);
    float4 b = *reinterpret_cast<const float4*>(in + i + 4);
    ushort o[8];
    o[0] = f2bf(a.x); o[1] = f2bf(a.y); o[2] = f2bf(a.z); o[3] = f2bf(a.w);
    o[4] = f2bf(b.x); o[5] = f2bf(b.y); o[6] = f2bf(b.z); o[7] = f2bf(b.w);
    *reinterpret_cast<int4*>(out + i) = *reinterpret_cast<const int4*>(o);
  }
}

// ---- 4 weight matrices (1M fp32 each) in ONE launch: saves 3 launches ----
__global__ __launch_bounds__(256) void cast4_kernel(const float* __restrict__ i0,
                                                    const float* __restrict__ i1,
                                                    const float* __restrict__ i2,
                                                    const float* __restrict__ i3,
                                                    ushort* __restrict__ o0,
                                                    ushort* __restrict__ o1,
                                                    ushort* __restrict__ o2,
                                                    ushort* __restrict__ o3) {
  const long n = 1048576L;
  long i = ((long)blockIdx.x * 256 + threadIdx.x) * 8;
  const long stride = (long)gridDim.x * 256 * 8;
  for (; i < n; i += stride) {
#pragma unroll
    for (int m = 0; m < 4; ++m) {
      const float* in = (m == 0) ? i0 : (m == 1) ? i1 : (m == 2) ? i2 : i3;
      ushort* out = (m == 0) ? o0 : (m == 1) ? o1 : (m == 2) ? o2 : o3;
      float4 a = *reinterpret_cast<const float4*>(in + i);
      float4 b = *reinterpret_cast<const float4*>(in + i + 4);
      ushort o[8];
      o[0] = f2bf(a.x); o[1] = f2bf(a.y); o[2] = f2bf(a.z); o[3] = f2bf(a.w);
      o[4] = f2bf(b.x); o[5] = f2bf(b.y); o[6] = f2bf(b.z); o[7] = f2bf(b.w);
      *reinterpret_cast<int4*>(out + i) = *reinterpret_cast<const int4*>(o);
    }
  }
}

// ---------------- 128x128 fused-cast GEMM, merged K+V ---------------------
// C = A(fp32) @ W(bf16)^T + bias, bf16 out. Tile 128(M)x128(N), BK=64.
// 256 thr = 4 waves (2x2 of 64x64), acc[4][4] = 64 AGPR, LDS 32KB.
// Per K-tile: sync; B via global_load_lds (verified gemm_lds pattern,
// pre-swizzled source); A via 8x float4 fp32 loads -> v_cvt_pk -> swizzled
// ds_write_b64 (verified gemm_bias pattern); sync; 32 MFMA.
// grid = 16384: blockIdx>>13 selects K or V quad; within a half,
// d = xcd + 8*bn + 64*m  ->  bm = xcd*128 + m (XCD-grouped, bn-adjacent).
__global__ __launch_bounds__(256)
void gemm_mid(const float* __restrict__ A0, const ushort* __restrict__ W0,
              const float* __restrict__ b0, ushort* __restrict__ C0,
              const float* __restrict__ A1, const ushort* __restrict__ W1,
              const float* __restrict__ b1, ushort* __restrict__ C1) {
  constexpr int K = 1024;
  __shared__ ushort lA[128 * 64];
  __shared__ ushort lB[128 * 64];
  const int tid = threadIdx.x;
  const int lane = tid & 63;
  const int wave = tid >> 6;
  const int wr = (wave >> 1) * 64;
  const int wc = (wave & 1) * 64;
  const int half_sel = blockIdx.x >> 13;  // 0 = K quad, 1 = V quad
  const int d = blockIdx.x & 8191;
  const float* Ag = half_sel ? A1 : A0;
  const ushort* Wg = half_sel ? W1 : W0;
  const float* bias = half_sel ? b1 : b0;
  ushort* Cg = half_sel ? C1 : C0;
  const int bn = (d >> 3) & 7;
  const size_t bm = (size_t)(d & 7) * 128 + (d >> 6);  // 8192/64 = 128 per XCD

  const float* aB = Ag + bm * 128 * K;
  const ushort* bB = Wg + (size_t)bn * 128 * K;
  const int srow = wave * 32 + (lane >> 3);
  const int scol = ((lane & 7) ^ (lane >> 3)) * 8;
  char* lAc = (char*)lA;
  char* lBc = (char*)lB;

  f32x4 acc[4][4] = {};

  for (int kt = 0; kt < K; kt += 64) {
    __syncthreads();
    // B: bf16 weights via global_load_lds (gemm_lds verified pattern)
#pragma unroll
    for (int c = 0; c < 4; ++c) {
      __builtin_amdgcn_global_load_lds(
          (gvp)(bB + (size_t)(srow + c * 8) * K + kt + scol),
          (lvp)(lBc + wave * 4096 + c * 1024), 16, 0, 0);
    }
    // A: fp32 reg-stage -> cvt_pk -> swizzled ds_write (gemm_bias pattern)
#pragma unroll
    for (int i = 0; i < 8; ++i) {
      int f = tid + i * 256;
      int row = f >> 4, c4 = f & 15;
      const float4 v = *reinterpret_cast<const float4*>(
          aB + (size_t)row * K + kt + c4 * 4);
      uint w0, w1;
      asm("v_cvt_pk_bf16_f32 %0,%1,%2" : "=v"(w0) : "v"(v.x), "v"(v.y));
      asm("v_cvt_pk_bf16_f32 %0,%1,%2" : "=v"(w1) : "v"(v.z), "v"(v.w));
      int byte = (row * 128 + c4 * 8) ^ ((row & 7) << 4);
      *reinterpret_cast<uint2*>(lAc + byte) = make_uint2(w0, w1);
    }
    __syncthreads();
#pragma unroll
    for (int kk = 0; kk < 2; ++kk) {
      bf16x8 af[4], bg[4];
#pragma unroll
      for (int fi = 0; fi < 4; ++fi) {
        int r = wr + fi * 16 + (lane & 15);
        int byte = (r * 128 + kk * 64 + ((lane >> 4) * 16)) ^ ((r & 7) << 4);
        af[fi] = *reinterpret_cast<const bf16x8*>(lAc + byte);
      }
#pragma unroll
      for (int fj = 0; fj < 4; ++fj) {
        int r = wc + fj * 16 + (lane & 15);
        int byte = (r * 128 + kk * 64 + ((lane >> 4) * 16)) ^ ((r & 7) << 4);
        bg[fj] = *reinterpret_cast<const bf16x8*>(lBc + byte);
      }
#pragma unroll
      for (int fi = 0; fi < 4; ++fi)
#pragma unroll
        for (int fj = 0; fj < 4; ++fj)
          acc[fi][fj] = __builtin_amdgcn_mfma_f32_16x16x32_bf16(af[fi], bg[fj],
                                                                acc[fi][fj], 0, 0, 0);
    }
  }
#pragma unroll
  for (int fi = 0; fi < 4; ++fi) {
#pragma unroll
    for (int fj = 0; fj < 4; ++fj) {
      int n = bn * 128 + wc + fj * 16 + (lane & 15);
      float bv = bias[n];
#pragma unroll
      for (int r = 0; r < 4; ++r) {
        size_t m = bm * 128 + wr + fi * 16 + ((lane >> 4) * 4) + r;
        Cg[m * 1024 + n] = f2bf(acc[fi][fj][r] + bv);
      }
    }
  }
}

// ---------------- 128x128 gload_lds GEMM (Q/O; verified) -------------------
template <typename TOUT>
__global__ __launch_bounds__(256) void gemm_lds(const ushort* __restrict__ Ag,
                                                const ushort* __restrict__ Wg,
                                                const float* __restrict__ bias,
                                                TOUT* __restrict__ Cg) {
  constexpr int K = 1024;
  __shared__ ushort lA[128 * 64];
  __shared__ ushort lB[128 * 64];
  const int tid = threadIdx.x;
  const int lane = tid & 63;
  const int wave = tid >> 6;
  const int wr = (wave >> 1) * 64;
  const int wc = (wave & 1) * 64;
  const int d = blockIdx.x;
  const int bn = (d >> 3) & 7;
  const size_t bm = (size_t)(d & 7) * (gridDim.x >> 6) + (d >> 6);

  const ushort* aB = Ag + bm * 128 * K;
  const ushort* bB = Wg + (size_t)bn * 128 * K;
  const int srow = wave * 32 + (lane >> 3);
  const int scol = ((lane & 7) ^ (lane >> 3)) * 8;
  char* lAc = (char*)lA;
  char* lBc = (char*)lB;

  f32x4 acc[4][4] = {};

  for (int kt = 0; kt < K; kt += 64) {
    __syncthreads();
#pragma unroll
    for (int c = 0; c < 4; ++c) {
      __builtin_amdgcn_global_load_lds(
          (gvp)(aB + (size_t)(srow + c * 8) * K + kt + scol),
          (lvp)(lAc + wave * 4096 + c * 1024), 16, 0, 0);
      __builtin_amdgcn_global_load_lds(
          (gvp)(bB + (size_t)(srow + c * 8) * K + kt + scol),
          (lvp)(lBc + wave * 4096 + c * 1024), 16, 0, 0);
    }
    __syncthreads();
#pragma unroll
    for (int kk = 0; kk < 2; ++kk) {
      bf16x8 af[4], bg[4];
#pragma unroll
      for (int fi = 0; fi < 4; ++fi) {
        int r = wr + fi * 16 + (lane & 15);
        int byte = (r * 128 + kk * 64 + ((lane >> 4) * 16)) ^ ((r & 7) << 4);
        af[fi] = *reinterpret_cast<const bf16x8*>(lAc + byte);
      }
#pragma unroll
      for (int fj = 0; fj < 4; ++fj) {
        int r = wc + fj * 16 + (lane & 15);
        int byte = (r * 128 + kk * 64 + ((lane >> 4) * 16)) ^ ((r & 7) << 4);
        bg[fj] = *reinterpret_cast<const bf16x8*>(lBc + byte);
      }
#pragma unroll
      for (int fi = 0; fi < 4; ++fi)
#pragma unroll
        for (int fj = 0; fj < 4; ++fj)
          acc[fi][fj] = __builtin_amdgcn_mfma_f32_16x16x32_bf16(af[fi], bg[fj],
                                                                acc[fi][fj], 0, 0, 0);
    }
  }
#pragma unroll
  for (int fi = 0; fi < 4; ++fi) {
#pragma unroll
    for (int fj = 0; fj < 4; ++fj) {
      int n = bn * 128 + wc + fj * 16 + (lane & 15);
      float bv = bias[n];
#pragma unroll
      for (int r = 0; r < 4; ++r) {
        size_t m = bm * 128 + wr + fi * 16 + ((lane >> 4) * 4) + r;
        float val = acc[fi][fj][r] + bv;
        if constexpr (sizeof(TOUT) == 2)
          reinterpret_cast<ushort*>(Cg)[m * 1024 + n] = f2bf(val);
        else
          reinterpret_cast<float*>(Cg)[m * 1024 + n] = val;
      }
    }
  }
}

// ------------- reg-staged GEMM (fp32 A): fallback path only ---------------
template <typename TIN, typename TOUT>
__global__ __launch_bounds__(256) void gemm_bias(const TIN* __restrict__ Ag,
                                                 const float* __restrict__ Wg,
                                                 const float* __restrict__ bias,
                                                 TOUT* __restrict__ Cg) {
  constexpr int K = 1024;
  __shared__ char lA[128 * 64 * 2];
  __shared__ char lB[128 * 64 * 2];
  const int tid = threadIdx.x;
  const int lane = tid & 63;
  const int wave = tid >> 6;
  const int wr = (wave >> 1) * 64;
  const int wc = (wave & 1) * 64;
  const int bn = blockIdx.x;
  const size_t bm = blockIdx.y;

  const TIN* aBase = Ag + bm * 128 * K;
  const float* bBase = Wg + (size_t)bn * 128 * K;

  f32x4 acc[4][4] = {};

  for (int kt = 0; kt < K; kt += 64) {
    __syncthreads();
    if constexpr (sizeof(TIN) == 4) {
#pragma unroll
      for (int i = 0; i < 8; ++i) {
        int f = tid + i * 256;
        int row = f >> 4, c4 = f & 15;
        const float4 v = *reinterpret_cast<const float4*>(
            reinterpret_cast<const float*>(aBase) + (size_t)row * K + kt + c4 * 4);
        ushort4 pk;
        pk.x = f2bf(v.x); pk.y = f2bf(v.y); pk.z = f2bf(v.z); pk.w = f2bf(v.w);
        int byte = (row * 128 + c4 * 8) ^ ((row & 7) << 4);
        *reinterpret_cast<ushort4*>(lA + byte) = pk;
      }
    } else {
#pragma unroll
      for (int i = 0; i < 4; ++i) {
        int f = tid + i * 256;
        int row = f >> 3, c8 = f & 7;
        int4 v = *reinterpret_cast<const int4*>(
            reinterpret_cast<const ushort*>(aBase) + (size_t)row * K + kt + c8 * 8);
        int byte = (row * 128 + c8 * 16) ^ ((row & 7) << 4);
        *reinterpret_cast<int4*>(lA + byte) = v;
      }
    }
#pragma unroll
    for (int i = 0; i < 8; ++i) {
      int f = tid + i * 256;
      int row = f >> 4, c4 = f & 15;
      const float4 v =
          *reinterpret_cast<const float4*>(bBase + (size_t)row * K + kt + c4 * 4);
      ushort4 pk;
      pk.x = f2bf(v.x); pk.y = f2bf(v.y); pk.z = f2bf(v.z); pk.w = f2bf(v.w);
      int byte = (row * 128 + c4 * 8) ^ ((row & 7) << 4);
      *reinterpret_cast<ushort4*>(lB + byte) = pk;
    }
    __syncthreads();
#pragma unroll
    for (int kk = 0; kk < 2; ++kk) {
      bf16x8 af[4], bg[4];
#pragma unroll
      for (int fi = 0; fi < 4; ++fi) {
        int r = wr + fi * 16 + (lane & 15);
        int byte = (r * 128 + kk * 64 + ((lane >> 4) * 16)) ^ ((r & 7) << 4);
        af[fi] = *reinterpret_cast<const bf16x8*>(lA + byte);
      }
#pragma unroll
      for (int fj = 0; fj < 4; ++fj) {
        int r = wc + fj * 16 + (lane & 15);
        int byte = (r * 128 + kk * 64 + ((lane >> 4) * 16)) ^ ((r & 7) << 4);
        bg[fj] = *reinterpret_cast<const bf16x8*>(lB + byte);
      }
#pragma unroll
      for (int fi = 0; fi < 4; ++fi)
#pragma unroll
        for (int fj = 0; fj < 4; ++fj)
          acc[fi][fj] =
              __builtin_amdgcn_mfma_f32_16x16x32_bf16(af[fi], bg[fj], acc[fi][fj], 0, 0, 0);
    }
  }
#pragma unroll
  for (int fi = 0; fi < 4; ++fi) {
#pragma unroll
    for (int fj = 0; fj < 4; ++fj) {
      int n = bn * 128 + wc + fj * 16 + (lane & 15);
      float bv = bias[n];
#pragma unroll
      for (int r = 0; r < 4; ++r) {
        size_t m = bm * 128 + wr + fi * 16 + ((lane >> 4) * 4) + r;
        float val = acc[fi][fj][r] + bv;
        if constexpr (sizeof(TOUT) == 2)
          reinterpret_cast<ushort*>(Cg)[m * 1024 + n] = f2bf(val);
        else
          reinterpret_cast<float*>(Cg)[m * 1024 + n] = val;
      }
    }
  }
}

// ---------------- attention: one block per (b,s'), head-axis softmax ------
__global__ __launch_bounds__(512) void attn_kernel(const ushort* __restrict__ Q,
                                                   const ushort* __restrict__ Kl,
                                                   const ushort* __restrict__ Vl,
                                                   ushort* __restrict__ Aout) {
  const int bs = blockIdx.x;
  const int b = bs >> 11, sp = bs & 2047;
  const int tid = threadIdx.x;
  const int wave = tid >> 6, lane = tid & 63;

  __shared__ ushort qrow[1024];
  __shared__ float sc[16][32];
  __shared__ float attnw[16][32];
  __shared__ float mx[32], rinv[32];

  reinterpret_cast<uint*>(qrow)[tid] =
      reinterpret_cast<const uint*>(Q + (size_t)bs * 1024)[tid];
  __syncthreads();

  const int wp = lane & 31, half = lane >> 5;
#pragma unroll
  for (int hh = 0; hh < 2; ++hh) {
    const int h = wave * 2 + hh;
    const int s_k = h * 128 + (sp >> 4);
    const int w_k = (sp & 15) * 2 + (wp >> 4);
    const ushort* kp =
        Kl + (((size_t)(b * 2048 + s_k) * 32) + w_k) * 1024 + (wp & 15) * 64 + half * 32;
    const ushort* qp = qrow + h * 64 + half * 32;
    float dot = 0.f;
#pragma unroll
    for (int j = 0; j < 32; j += 8) {
      int4 kv = *reinterpret_cast<const int4*>(kp + j);
      int4 qv = *reinterpret_cast<const int4*>(qp + j);
      const ushort* ka = reinterpret_cast<const ushort*>(&kv);
      const ushort* qa = reinterpret_cast<const ushort*>(&qv);
#pragma unroll
      for (int t = 0; t < 8; ++t) dot += bf2f(ka[t]) * bf2f(qa[t]);
    }
    dot += __shfl_xor(dot, 32);
    if (half == 0) sc[h][wp] = dot * 0.125f;
  }
  __syncthreads();
  if (tid < 32) {
    float m = sc[0][tid];
#pragma unroll
    for (int h = 1; h < 16; ++h) m = fmaxf(m, sc[h][tid]);
    float s = 0.f;
#pragma unroll
    for (int h = 0; h < 16; ++h) s += __expf(sc[h][tid] - m);
    mx[tid] = m;
    rinv[tid] = 1.f / s;
  }
  __syncthreads();
  if (lane < 32) {
#pragma unroll
    for (int hh = 0; hh < 2; ++hh) {
      const int h = wave * 2 + hh;
      attnw[h][lane] = __expf(sc[h][lane] - mx[lane]) * rinv[lane];
    }
  }
  __syncthreads();
#pragma unroll
  for (int hh = 0; hh < 2; ++hh) {
    const int h = wave * 2 + hh;
    const int s_k = h * 128 + (sp >> 4);
    const size_t vb = (((size_t)(b * 2048 + s_k) * 32) + (sp & 15) * 2) * 1024;
    float a = 0.f;
#pragma unroll
    for (int w2 = 0; w2 < 32; ++w2) {
      float wgt = attnw[h][w2];
      a += wgt * bf2f(Vl[vb + (size_t)(w2 >> 4) * 1024 + (w2 & 15) * 64 + lane]);
    }
    Aout[(((size_t)(b * 16 + h)) * 2048 + sp) * 64 + lane] = f2bf(a);
  }
}

extern "C" void kernel_launch(void* const* d_in, const int* in_sizes, int n_in,
                              void* d_out, int out_size, void* d_ws, size_t ws_size,
                              hipStream_t stream) {
  const float* q = (const float*)d_in[0];
  const float* k = (const float*)d_in[1];
  const float* v = (const float*)d_in[2];
  const float* Wq = (const float*)d_in[3];
  const float* bq = (const float*)d_in[4];
  const float* Wk = (const float*)d_in[5];
  const float* bk = (const float*)d_in[6];
  const float* Wv = (const float*)d_in[7];
  const float* bv = (const float*)d_in[8];
  const float* Wo = (const float*)d_in[9];
  const float* bo = (const float*)d_in[10];
  float* out = (float*)d_out;

  char* ws = (char*)d_ws;
  const size_t MB = 1u << 20;
  ushort* Qlin = (ushort*)ws;                    // 8 MiB
  ushort* Aws  = (ushort*)(ws + 8 * MB);         // 8 MiB
  ushort* wkbf = (ushort*)(ws + 16 * MB);        // 2 MiB
  ushort* wvbf = (ushort*)(ws + 18 * MB);        // 2 MiB
  ushort* wqbf = (ushort*)(ws + 20 * MB);        // 2 MiB
  ushort* wobf = (ushort*)(ws + 22 * MB);        // 2 MiB
  ushort* qbf  = (ushort*)(ws + 24 * MB);        // 8 MiB
  ushort* Klin = (ushort*)(ws + 32 * MB);        // 256 MiB
  ushort* Vlin = (ushort*)(ws + 288 * MB);       // 256 MiB
  const bool full = ws_size >= 800 * MB;

  if (full) {
    cast4_kernel<<<dim3(512), 256, 0, stream>>>(Wq, Wk, Wv, Wo,
                                                wqbf, wkbf, wvbf, wobf);
    cast_kernel<<<dim3(2048), 256, 0, stream>>>(q, qbf, 4194304L);
    gemm_lds<ushort><<<dim3(256), 256, 0, stream>>>(qbf, wqbf, bq, Qlin);
    // K + V GEMMs merged: 128x128 fused-cast, 16384 blocks
    gemm_mid<<<dim3(16384), 256, 0, stream>>>(k, wkbf, bk, Klin,
                                              v, wvbf, bv, Vlin);
    attn_kernel<<<dim3(4096), dim3(512), 0, stream>>>(Qlin, Klin, Vlin, Aws);
    gemm_lds<float><<<dim3(256), 256, 0, stream>>>(Aws, wobf, bo, out);
  } else {
    gemm_bias<float, ushort><<<dim3(8, 32), 256, 0, stream>>>(q, Wq, bq, Qlin);
    gemm_bias<float, ushort><<<dim3(8, 1024), 256, 0, stream>>>(k, Wk, bk, Klin);
    gemm_bias<float, ushort><<<dim3(8, 1024), 256, 0, stream>>>(v, Wv, bv, Vlin);
    attn_kernel<<<dim3(4096), dim3(512), 0, stream>>>(Qlin, Klin, Vlin, Aws);
    gemm_bias<ushort, float><<<dim3(8, 32), 256, 0, stream>>>(Aws, Wo, bo, out);
  }
}

// Round 18
// 859.263 us; speedup vs baseline: 1.4618x; 1.4618x over previous
//
#include <hip/hip_runtime.h>
#include <hip/hip_bf16.h>

// B=2, S=2048, W=32, D=1024, H=16, hd=64
// Pipeline (full path) — SESSION-BEST CONFIG (round 16, 859.3us):
//   bf16-cast: cast4_kernel (Wq,Wk,Wv,Wo in one launch), q (cast_kernel)
//   K+V GEMM: gemm_big MERGED single launch (4096 blocks; d>>11 selects
//             K or V; body = round-15 verified kernel: fused fp32->bf16
//             A-cast, 3-slot B ring, zero manual vmcnt in loop, 2 sync
//             points/iter). Session post-mortem: seven schedule variants
//             plateau at ~370-430us/GEMM, 27-32% MfmaUtil — acc[8][4]=128
//             AGPR pins 2 waves/SIMD (extra loop-carried regs spill,
//             r10-12); the 128^2 fused-cast occupancy attempt (r17)
//             regressed to 1165us (serial cast chain, VALUBusy 29.5%).
//   Q/O GEMM: gemm_lds (128x128)
//   attn: per (b,s') head-softmax gather-attention -> A (4096x1024 bf16)
//   out  = A@Wo^T+bo (fp32)

#define DEVI __device__ __forceinline__

typedef __attribute__((ext_vector_type(8))) short bf16x8;
typedef __attribute__((ext_vector_type(4))) float f32x4;
typedef const __attribute__((address_space(1))) void* gvp;
typedef __attribute__((address_space(3))) void* lvp;

DEVI ushort f2bf(float f) {
  uint u = __float_as_uint(f);
  u = u + 0x7fffu + ((u >> 16) & 1u);
  return (ushort)(u >> 16);
}
DEVI float bf2f(ushort u) { return __uint_as_float(((uint)u) << 16); }

// ---------------- elementwise fp32 -> bf16 cast (RNE), 8 elems/thread ----
__global__ __launch_bounds__(256) void cast_kernel(const float* __restrict__ in,
                                                   ushort* __restrict__ out,
                                                   long n) {
  long i = ((long)blockIdx.x * 256 + threadIdx.x) * 8;
  const long stride = (long)gridDim.x * 256 * 8;
  for (; i < n; i += stride) {
    float4 a = *reinterpret_cast<const float4*>(in + i);
    float4 b = *reinterpret_cast<const float4*>(in + i + 4);
    ushort o[8];
    o[0] = f2bf(a.x); o[1] = f2bf(a.y); o[2] = f2bf(a.z); o[3] = f2bf(a.w);
    o[4] = f2bf(b.x); o[5] = f2bf(b.y); o[6] = f2bf(b.z); o[7] = f2bf(b.w);
    *reinterpret_cast<int4*>(out + i) = *reinterpret_cast<const int4*>(o);
  }
}

// ---- 4 weight matrices (1M fp32 each) in ONE launch: saves 3 launches ----
__global__ __launch_bounds__(256) void cast4_kernel(const float* __restrict__ i0,
                                                    const float* __restrict__ i1,
                                                    const float* __restrict__ i2,
                                                    const float* __restrict__ i3,
                                                    ushort* __restrict__ o0,
                                                    ushort* __restrict__ o1,
                                                    ushort* __restrict__ o2,
                                                    ushort* __restrict__ o3) {
  const long n = 1048576L;
  long i = ((long)blockIdx.x * 256 + threadIdx.x) * 8;
  const long stride = (long)gridDim.x * 256 * 8;
  for (; i < n; i += stride) {
#pragma unroll
    for (int m = 0; m < 4; ++m) {
      const float* in = (m == 0) ? i0 : (m == 1) ? i1 : (m == 2) ? i2 : i3;
      ushort* out = (m == 0) ? o0 : (m == 1) ? o1 : (m == 2) ? o2 : o3;
      float4 a = *reinterpret_cast<const float4*>(in + i);
      float4 b = *reinterpret_cast<const float4*>(in + i + 4);
      ushort o[8];
      o[0] = f2bf(a.x); o[1] = f2bf(a.y); o[2] = f2bf(a.z); o[3] = f2bf(a.w);
      o[4] = f2bf(b.x); o[5] = f2bf(b.y); o[6] = f2bf(b.z); o[7] = f2bf(b.w);
      *reinterpret_cast<int4*>(out + i) = *reinterpret_cast<const int4*>(o);
    }
  }
}

// ---------------- fused-cast B-ring-3 GEMM, merged K+V --------------------
// C = A(fp32) @ W(bf16)^T + bias, bf16 out. Tile 256x256, BK=64, 16 K-tiles,
// 8 iters x 2 tiles. LDS 160K: buf0.A @0 (32K), buf1.A @32K, B ring slots
// 0/1/2 @ 64K+s*32K. Row = 128B = 8 chunks of 16B; stored chunk p of row r
// holds source chunk p^(r&7); fragment read swz ((kk*4+q)^(lm&7))*16.
// grid = 4096: d>>11 selects the (A,W,bias,C) quad (K or V); block body
// byte-identical to the round-15 verified kernel.
template <int FJ0>
DEVI void mfma16b(f32x4 (&acc)[8][4], const bf16x8 (&A)[8], const bf16x8 (&B)[2]) {
  __builtin_amdgcn_s_setprio(1);
#pragma unroll
  for (int fi = 0; fi < 8; ++fi)
#pragma unroll
    for (int j = 0; j < 2; ++j)
      acc[fi][FJ0 + j] = __builtin_amdgcn_mfma_f32_16x16x32_bf16(
          A[fi], B[j], acc[fi][FJ0 + j], 0, 0, 0);
  __builtin_amdgcn_s_setprio(0);
}

__global__ __launch_bounds__(512)
__attribute__((amdgpu_waves_per_eu(2, 2)))
void gemm_big(const float* __restrict__ A0, const ushort* __restrict__ W0,
              const float* __restrict__ b0, ushort* __restrict__ C0,
              const float* __restrict__ A1, const ushort* __restrict__ W1,
              const float* __restrict__ b1, ushort* __restrict__ C1) {
  constexpr int K = 1024;
  __shared__ char lds[163840];
  const int tid = threadIdx.x;
  const int lane = tid & 63;
  const int wave = tid >> 6;
  const int wm = wave >> 2;
  const int wn = wave & 3;
  const int half_sel = blockIdx.x >> 11;      // 0 = K quad, 1 = V quad
  const int d = blockIdx.x & 2047;            // block id within the half
  const float* Ag = half_sel ? A1 : A0;
  const ushort* Wg = half_sel ? W1 : W0;
  const float* bias = half_sel ? b1 : b0;
  ushort* Cg = half_sel ? C1 : C0;
  const int bn = (d >> 3) & 3;
  const size_t bm = (size_t)(d & 7) * 64 + (d >> 5);  // 2048/32 = 64 per XCD

  const ushort* bB = Wg + (size_t)bn * 256 * K;

  const int r0 = tid >> 3;
  const int c0 = (tid & 7) ^ (r0 & 7);
  const float* pR0 = Ag + bm * 256 * K + (size_t)r0 * K + c0 * 8;
  const float* pR1 = pR0 + 64 * K;
  const ushort* bS0 = bB + (size_t)r0 * K + c0 * 8;
  const ushort* bS1 = bB + (size_t)(r0 + 64) * K + c0 * 8;
  const ushort* bS2 = bB + (size_t)(r0 + 128) * K + c0 * 8;
  const ushort* bS3 = bB + (size_t)(r0 + 192) * K + c0 * 8;

  const int lm = lane & 15;
  const int q = lane >> 4;
  const int rowB = lm * 128;
  const int swz0 = (q ^ (lm & 7)) * 16;
  const int swz1 = ((4 + q) ^ (lm & 7)) * 16;
  const char* ldsc = (const char*)lds;
  const char* p0A = ldsc + wm * 16384 + rowB;
  const char* p1A = p0A + 32768;
  const int bOff = (wn >> 1) * 16384 + (wn & 1) * 8192 + rowB;

  f32x4 acc[8][4] = {};
  bf16x8 A8[8];
  bf16x8 Bf[2];
  float4 st[8];  // single shared staging set (intra-iteration liveness only)

#define SB0 __builtin_amdgcn_sched_barrier(0)
#define BAR __builtin_amdgcn_s_barrier()
#define STG(p0, p1, ktE, ldsOff)                                                 \
  {                                                                              \
    __builtin_amdgcn_global_load_lds((gvp)((p0) + (ktE)),                        \
                                     (lvp)(lds + (ldsOff) + tid * 16), 16, 0, 0);\
    __builtin_amdgcn_global_load_lds((gvp)((p1) + (ktE)),                        \
                                     (lvp)(lds + (ldsOff) + 8192 + tid * 16),    \
                                     16, 0, 0);                                  \
  }
#define AISS8(off)                                                      \
  {                                                                     \
    st[0] = *reinterpret_cast<const float4*>(pR0 + (off));              \
    st[1] = *reinterpret_cast<const float4*>(pR0 + (off) + 4);          \
    st[2] = *reinterpret_cast<const float4*>(pR1 + (off));              \
    st[3] = *reinterpret_cast<const float4*>(pR1 + (off) + 4);          \
    st[4] = *reinterpret_cast<const float4*>(pR0 + 131072 + (off));     \
    st[5] = *reinterpret_cast<const float4*>(pR0 + 131072 + (off) + 4); \
    st[6] = *reinterpret_cast<const float4*>(pR1 + 131072 + (off));     \
    st[7] = *reinterpret_cast<const float4*>(pR1 + 131072 + (off) + 4); \
  }
#define CVTPAIR(v0, v1, dstoff)                                              \
  {                                                                          \
    uint w0, w1, w2, w3;                                                     \
    asm("v_cvt_pk_bf16_f32 %0,%1,%2" : "=v"(w0) : "v"((v0).x), "v"((v0).y)); \
    asm("v_cvt_pk_bf16_f32 %0,%1,%2" : "=v"(w1) : "v"((v0).z), "v"((v0).w)); \
    asm("v_cvt_pk_bf16_f32 %0,%1,%2" : "=v"(w2) : "v"((v1).x), "v"((v1).y)); \
    asm("v_cvt_pk_bf16_f32 %0,%1,%2" : "=v"(w3) : "v"((v1).z), "v"((v1).w)); \
    *reinterpret_cast<uint4*>(lds + (dstoff) + tid * 16) =                   \
        make_uint4(w0, w1, w2, w3);                                          \
  }
#define CVT8(base)                          \
  {                                         \
    CVTPAIR(st[0], st[1], (base));          \
    CVTPAIR(st[2], st[3], (base) + 8192);   \
    CVTPAIR(st[4], st[5], (base) + 16384);  \
    CVTPAIR(st[6], st[7], (base) + 24576);  \
  }
#define LDA8(p, swz)                                                       \
  _Pragma("unroll") for (int i_ = 0; i_ < 8; ++i_) {                       \
    A8[i_] = *reinterpret_cast<const bf16x8*>((p) + i_ * 2048 + (swz));    \
  }
#define LDB2(p, fjb, swz)                                                  \
  {                                                                        \
    Bf[0] = *reinterpret_cast<const bf16x8*>((p) + (fjb) + (swz));         \
    Bf[1] = *reinterpret_cast<const bf16x8*>((p) + (fjb) + 2048 + (swz));  \
  }

  // ---- prologue: A(0) cvt -> buf0.A; B(0)->slot0, B(1)->slot1;
  // AISS A(1) left in flight (drained by it0-P1's CVT).
  AISS8(0); SB0;
  CVT8(0);  // auto-drain; writes buf0.A(0)
  SB0;
  STG(bS0, bS1, 0, 65536); STG(bS2, bS3, 0, 65536 + 16384); SB0;
  STG(bS0, bS1, 64, 98304); STG(bS2, bS3, 64, 98304 + 16384); SB0;
  AISS8(64); SB0;  // A(1)
  asm volatile("s_waitcnt vmcnt(8)" ::: "memory");  // drain B(0),B(1)
  asm volatile("s_waitcnt lgkmcnt(0)" ::: "memory");
  BAR;
  SB0;

#define ITER(M, RA, RB, SC, SD)                                           \
  {                                                                       \
    const int ktB2 = (2 * it + 2) * 64;                                   \
    const int ktB3 = (2 * it + 3) * 64;                                   \
    const char* pBa = ldsc + 65536 + (RA) * 32768 + bOff;                 \
    const char* pBb = ldsc + 65536 + (RB) * 32768 + bOff;                 \
    /* P1: buf0.A/B[RA] kk0; STG B(j+2)->SC; CVT st->buf1.A(j+1); AISS */ \
    LDA8(p0A, swz0); LDB2(pBa, 0, swz0);                                  \
    if (M == 0) {                                                         \
      STG(bS0, bS1, ktB2, 65536 + (SC) * 32768);                          \
      STG(bS2, bS3, ktB2, 65536 + (SC) * 32768 + 16384);                  \
    }                                                                     \
    CVT8(32768);                                                          \
    SB0;                                                                  \
    if (M == 0) { AISS8(ktB2); SB0; }                                     \
    mfma16b<0>(acc, A8, Bf);                                              \
    LDB2(pBa, 4096, swz0);                                                \
    mfma16b<2>(acc, A8, Bf);                                              \
    /* P2: kk1; end: publish P1 LDS writes */                             \
    LDA8(p0A, swz1); LDB2(pBa, 0, swz1);                                  \
    mfma16b<0>(acc, A8, Bf);                                              \
    LDB2(pBa, 4096, swz1);                                                \
    mfma16b<2>(acc, A8, Bf);                                              \
    SB0;                                                                  \
    asm volatile("s_waitcnt lgkmcnt(0)" ::: "memory");                    \
    BAR; SB0;                                                             \
    /* P3: buf1.A/B[RB] kk0; STG B(j+3)->SD; CVT st->buf0.A(j+2); AISS */ \
    LDA8(p1A, swz0); LDB2(pBb, 0, swz0);                                  \
    if (M == 0) {                                                         \
      STG(bS0, bS1, ktB3, 65536 + (SD) * 32768);                          \
      STG(bS2, bS3, ktB3, 65536 + (SD) * 32768 + 16384);                  \
      CVT8(0);                                                            \
      SB0;                                                                \
      AISS8(ktB3);                                                        \
      SB0;                                                                \
    }                                                                     \
    mfma16b<0>(acc, A8, Bf);                                              \
    LDB2(pBb, 4096, swz0);                                                \
    mfma16b<2>(acc, A8, Bf);                                              \
    /* P4: kk1; end: publish P3 LDS writes */                             \
    LDA8(p1A, swz1); LDB2(pBb, 0, swz1);                                  \
    mfma16b<0>(acc, A8, Bf);                                              \
    LDB2(pBb, 4096, swz1);                                                \
    mfma16b<2>(acc, A8, Bf);                                              \
    if (M == 0) {                                                         \
      SB0;                                                                \
      asm volatile("s_waitcnt lgkmcnt(0)" ::: "memory");                  \
      BAR; SB0;                                                           \
    }                                                                     \
  }

#pragma unroll 1
  for (int g = 0; g < 2; ++g) {
    { const int it = 3 * g;     ITER(0, 0, 1, 2, 0) }
    { const int it = 3 * g + 1; ITER(0, 2, 0, 1, 2) }
    { const int it = 3 * g + 2; ITER(0, 1, 2, 0, 1) }
  }
  { const int it = 6; ITER(0, 0, 1, 2, 0) }
  { const int it = 7; ITER(1, 2, 0, 1, 2) }
#undef ITER
#undef STG
#undef AISS8
#undef CVTPAIR
#undef CVT8
#undef LDA8
#undef LDB2
#undef SB0
#undef BAR

  // ---- epilogue: C/D layout col=lane&15, row=(lane>>4)*4+r ----
#pragma unroll
  for (int fi = 0; fi < 8; ++fi) {
#pragma unroll
    for (int fj = 0; fj < 4; ++fj) {
      int n = bn * 256 + wn * 64 + fj * 16 + lm;
      float bv = bias[n];
#pragma unroll
      for (int r = 0; r < 4; ++r) {
        size_t m = bm * 256 + wm * 128 + fi * 16 + ((lane >> 4) * 4) + r;
        Cg[m * 1024 + n] = f2bf(acc[fi][fj][r] + bv);
      }
    }
  }
}

// ---------------- 128x128 gload_lds GEMM (Q/O; verified) -------------------
template <typename TOUT>
__global__ __launch_bounds__(256) void gemm_lds(const ushort* __restrict__ Ag,
                                                const ushort* __restrict__ Wg,
                                                const float* __restrict__ bias,
                                                TOUT* __restrict__ Cg) {
  constexpr int K = 1024;
  __shared__ ushort lA[128 * 64];
  __shared__ ushort lB[128 * 64];
  const int tid = threadIdx.x;
  const int lane = tid & 63;
  const int wave = tid >> 6;
  const int wr = (wave >> 1) * 64;
  const int wc = (wave & 1) * 64;
  const int d = blockIdx.x;
  const int bn = (d >> 3) & 7;
  const size_t bm = (size_t)(d & 7) * (gridDim.x >> 6) + (d >> 6);

  const ushort* aB = Ag + bm * 128 * K;
  const ushort* bB = Wg + (size_t)bn * 128 * K;
  const int srow = wave * 32 + (lane >> 3);
  const int scol = ((lane & 7) ^ (lane >> 3)) * 8;
  char* lAc = (char*)lA;
  char* lBc = (char*)lB;

  f32x4 acc[4][4] = {};

  for (int kt = 0; kt < K; kt += 64) {
    __syncthreads();
#pragma unroll
    for (int c = 0; c < 4; ++c) {
      __builtin_amdgcn_global_load_lds(
          (gvp)(aB + (size_t)(srow + c * 8) * K + kt + scol),
          (lvp)(lAc + wave * 4096 + c * 1024), 16, 0, 0);
      __builtin_amdgcn_global_load_lds(
          (gvp)(bB + (size_t)(srow + c * 8) * K + kt + scol),
          (lvp)(lBc + wave * 4096 + c * 1024), 16, 0, 0);
    }
    __syncthreads();
#pragma unroll
    for (int kk = 0; kk < 2; ++kk) {
      bf16x8 af[4], bg[4];
#pragma unroll
      for (int fi = 0; fi < 4; ++fi) {
        int r = wr + fi * 16 + (lane & 15);
        int byte = (r * 128 + kk * 64 + ((lane >> 4) * 16)) ^ ((r & 7) << 4);
        af[fi] = *reinterpret_cast<const bf16x8*>(lAc + byte);
      }
#pragma unroll
      for (int fj = 0; fj < 4; ++fj) {
        int r = wc + fj * 16 + (lane & 15);
        int byte = (r * 128 + kk * 64 + ((lane >> 4) * 16)) ^ ((r & 7) << 4);
        bg[fj] = *reinterpret_cast<const bf16x8*>(lBc + byte);
      }
#pragma unroll
      for (int fi = 0; fi < 4; ++fi)
#pragma unroll
        for (int fj = 0; fj < 4; ++fj)
          acc[fi][fj] = __builtin_amdgcn_mfma_f32_16x16x32_bf16(af[fi], bg[fj],
                                                                acc[fi][fj], 0, 0, 0);
    }
  }
#pragma unroll
  for (int fi = 0; fi < 4; ++fi) {
#pragma unroll
    for (int fj = 0; fj < 4; ++fj) {
      int n = bn * 128 + wc + fj * 16 + (lane & 15);
      float bv = bias[n];
#pragma unroll
      for (int r = 0; r < 4; ++r) {
        size_t m = bm * 128 + wr + fi * 16 + ((lane >> 4) * 4) + r;
        float val = acc[fi][fj][r] + bv;
        if constexpr (sizeof(TOUT) == 2)
          reinterpret_cast<ushort*>(Cg)[m * 1024 + n] = f2bf(val);
        else
          reinterpret_cast<float*>(Cg)[m * 1024 + n] = val;
      }
    }
  }
}

// ------------- reg-staged GEMM (fp32 A): fallback path only ---------------
template <typename TIN, typename TOUT>
__global__ __launch_bounds__(256) void gemm_bias(const TIN* __restrict__ Ag,
                                                 const float* __restrict__ Wg,
                                                 const float* __restrict__ bias,
                                                 TOUT* __restrict__ Cg) {
  constexpr int K = 1024;
  __shared__ char lA[128 * 64 * 2];
  __shared__ char lB[128 * 64 * 2];
  const int tid = threadIdx.x;
  const int lane = tid & 63;
  const int wave = tid >> 6;
  const int wr = (wave >> 1) * 64;
  const int wc = (wave & 1) * 64;
  const int bn = blockIdx.x;
  const size_t bm = blockIdx.y;

  const TIN* aBase = Ag + bm * 128 * K;
  const float* bBase = Wg + (size_t)bn * 128 * K;

  f32x4 acc[4][4] = {};

  for (int kt = 0; kt < K; kt += 64) {
    __syncthreads();
    if constexpr (sizeof(TIN) == 4) {
#pragma unroll
      for (int i = 0; i < 8; ++i) {
        int f = tid + i * 256;
        int row = f >> 4, c4 = f & 15;
        const float4 v = *reinterpret_cast<const float4*>(
            reinterpret_cast<const float*>(aBase) + (size_t)row * K + kt + c4 * 4);
        ushort4 pk;
        pk.x = f2bf(v.x); pk.y = f2bf(v.y); pk.z = f2bf(v.z); pk.w = f2bf(v.w);
        int byte = (row * 128 + c4 * 8) ^ ((row & 7) << 4);
        *reinterpret_cast<ushort4*>(lA + byte) = pk;
      }
    } else {
#pragma unroll
      for (int i = 0; i < 4; ++i) {
        int f = tid + i * 256;
        int row = f >> 3, c8 = f & 7;
        int4 v = *reinterpret_cast<const int4*>(
            reinterpret_cast<const ushort*>(aBase) + (size_t)row * K + kt + c8 * 8);
        int byte = (row * 128 + c8 * 16) ^ ((row & 7) << 4);
        *reinterpret_cast<int4*>(lA + byte) = v;
      }
    }
#pragma unroll
    for (int i = 0; i < 8; ++i) {
      int f = tid + i * 256;
      int row = f >> 4, c4 = f & 15;
      const float4 v =
          *reinterpret_cast<const float4*>(bBase + (size_t)row * K + kt + c4 * 4);
      ushort4 pk;
      pk.x = f2bf(v.x); pk.y = f2bf(v.y); pk.z = f2bf(v.z); pk.w = f2bf(v.w);
      int byte = (row * 128 + c4 * 8) ^ ((row & 7) << 4);
      *reinterpret_cast<ushort4*>(lB + byte) = pk;
    }
    __syncthreads();
#pragma unroll
    for (int kk = 0; kk < 2; ++kk) {
      bf16x8 af[4], bg[4];
#pragma unroll
      for (int fi = 0; fi < 4; ++fi) {
        int r = wr + fi * 16 + (lane & 15);
        int byte = (r * 128 + kk * 64 + ((lane >> 4) * 16)) ^ ((r & 7) << 4);
        af[fi] = *reinterpret_cast<const bf16x8*>(lA + byte);
      }
#pragma unroll
      for (int fj = 0; fj < 4; ++fj) {
        int r = wc + fj * 16 + (lane & 15);
        int byte = (r * 128 + kk * 64 + ((lane >> 4) * 16)) ^ ((r & 7) << 4);
        bg[fj] = *reinterpret_cast<const bf16x8*>(lB + byte);
      }
#pragma unroll
      for (int fi = 0; fi < 4; ++fi)
#pragma unroll
        for (int fj = 0; fj < 4; ++fj)
          acc[fi][fj] =
              __builtin_amdgcn_mfma_f32_16x16x32_bf16(af[fi], bg[fj], acc[fi][fj], 0, 0, 0);
    }
  }
#pragma unroll
  for (int fi = 0; fi < 4; ++fi) {
#pragma unroll
    for (int fj = 0; fj < 4; ++fj) {
      int n = bn * 128 + wc + fj * 16 + (lane & 15);
      float bv = bias[n];
#pragma unroll
      for (int r = 0; r < 4; ++r) {
        size_t m = bm * 128 + wr + fi * 16 + ((lane >> 4) * 4) + r;
        float val = acc[fi][fj][r] + bv;
        if constexpr (sizeof(TOUT) == 2)
          reinterpret_cast<ushort*>(Cg)[m * 1024 + n] = f2bf(val);
        else
          reinterpret_cast<float*>(Cg)[m * 1024 + n] = val;
      }
    }
  }
}

// ---------------- attention: one block per (b,s'), head-axis softmax ------
__global__ __launch_bounds__(512) void attn_kernel(const ushort* __restrict__ Q,
                                                   const ushort* __restrict__ Kl,
                                                   const ushort* __restrict__ Vl,
                                                   ushort* __restrict__ Aout) {
  const int bs = blockIdx.x;
  const int b = bs >> 11, sp = bs & 2047;
  const int tid = threadIdx.x;
  const int wave = tid >> 6, lane = tid & 63;

  __shared__ ushort qrow[1024];
  __shared__ float sc[16][32];
  __shared__ float attnw[16][32];
  __shared__ float mx[32], rinv[32];

  reinterpret_cast<uint*>(qrow)[tid] =
      reinterpret_cast<const uint*>(Q + (size_t)bs * 1024)[tid];
  __syncthreads();

  const int wp = lane & 31, half = lane >> 5;
#pragma unroll
  for (int hh = 0; hh < 2; ++hh) {
    const int h = wave * 2 + hh;
    const int s_k = h * 128 + (sp >> 4);
    const int w_k = (sp & 15) * 2 + (wp >> 4);
    const ushort* kp =
        Kl + (((size_t)(b * 2048 + s_k) * 32) + w_k) * 1024 + (wp & 15) * 64 + half * 32;
    const ushort* qp = qrow + h * 64 + half * 32;
    float dot = 0.f;
#pragma unroll
    for (int j = 0; j < 32; j += 8) {
      int4 kv = *reinterpret_cast<const int4*>(kp + j);
      int4 qv = *reinterpret_cast<const int4*>(qp + j);
      const ushort* ka = reinterpret_cast<const ushort*>(&kv);
      const ushort* qa = reinterpret_cast<const ushort*>(&qv);
#pragma unroll
      for (int t = 0; t < 8; ++t) dot += bf2f(ka[t]) * bf2f(qa[t]);
    }
    dot += __shfl_xor(dot, 32);
    if (half == 0) sc[h][wp] = dot * 0.125f;
  }
  __syncthreads();
  if (tid < 32) {
    float m = sc[0][tid];
#pragma unroll
    for (int h = 1; h < 16; ++h) m = fmaxf(m, sc[h][tid]);
    float s = 0.f;
#pragma unroll
    for (int h = 0; h < 16; ++h) s += __expf(sc[h][tid] - m);
    mx[tid] = m;
    rinv[tid] = 1.f / s;
  }
  __syncthreads();
  if (lane < 32) {
#pragma unroll
    for (int hh = 0; hh < 2; ++hh) {
      const int h = wave * 2 + hh;
      attnw[h][lane] = __expf(sc[h][lane] - mx[lane]) * rinv[lane];
    }
  }
  __syncthreads();
#pragma unroll
  for (int hh = 0; hh < 2; ++hh) {
    const int h = wave * 2 + hh;
    const int s_k = h * 128 + (sp >> 4);
    const size_t vb = (((size_t)(b * 2048 + s_k) * 32) + (sp & 15) * 2) * 1024;
    float a = 0.f;
#pragma unroll
    for (int w2 = 0; w2 < 32; ++w2) {
      float wgt = attnw[h][w2];
      a += wgt * bf2f(Vl[vb + (size_t)(w2 >> 4) * 1024 + (w2 & 15) * 64 + lane]);
    }
    Aout[(((size_t)(b * 16 + h)) * 2048 + sp) * 64 + lane] = f2bf(a);
  }
}

extern "C" void kernel_launch(void* const* d_in, const int* in_sizes, int n_in,
                              void* d_out, int out_size, void* d_ws, size_t ws_size,
                              hipStream_t stream) {
  const float* q = (const float*)d_in[0];
  const float* k = (const float*)d_in[1];
  const float* v = (const float*)d_in[2];
  const float* Wq = (const float*)d_in[3];
  const float* bq = (const float*)d_in[4];
  const float* Wk = (const float*)d_in[5];
  const float* bk = (const float*)d_in[6];
  const float* Wv = (const float*)d_in[7];
  const float* bv = (const float*)d_in[8];
  const float* Wo = (const float*)d_in[9];
  const float* bo = (const float*)d_in[10];
  float* out = (float*)d_out;

  char* ws = (char*)d_ws;
  const size_t MB = 1u << 20;
  ushort* Qlin = (ushort*)ws;                    // 8 MiB
  ushort* Aws  = (ushort*)(ws + 8 * MB);         // 8 MiB
  ushort* wkbf = (ushort*)(ws + 16 * MB);        // 2 MiB
  ushort* wvbf = (ushort*)(ws + 18 * MB);        // 2 MiB
  ushort* wqbf = (ushort*)(ws + 20 * MB);        // 2 MiB
  ushort* wobf = (ushort*)(ws + 22 * MB);        // 2 MiB
  ushort* qbf  = (ushort*)(ws + 24 * MB);        // 8 MiB
  ushort* Klin = (ushort*)(ws + 32 * MB);        // 256 MiB
  ushort* Vlin = (ushort*)(ws + 288 * MB);       // 256 MiB
  const bool full = ws_size >= 800 * MB;

  if (full) {
    cast4_kernel<<<dim3(512), 256, 0, stream>>>(Wq, Wk, Wv, Wo,
                                                wqbf, wkbf, wvbf, wobf);
    cast_kernel<<<dim3(2048), 256, 0, stream>>>(q, qbf, 4194304L);
    gemm_lds<ushort><<<dim3(256), 256, 0, stream>>>(qbf, wqbf, bq, Qlin);
    // K + V GEMMs merged into one 4096-block launch
    gemm_big<<<dim3(4096), 512, 0, stream>>>(k, wkbf, bk, Klin,
                                             v, wvbf, bv, Vlin);
    attn_kernel<<<dim3(4096), dim3(512), 0, stream>>>(Qlin, Klin, Vlin, Aws);
    gemm_lds<float><<<dim3(256), 256, 0, stream>>>(Aws, wobf, bo, out);
  } else {
    gemm_bias<float, ushort><<<dim3(8, 32), 256, 0, stream>>>(q, Wq, bq, Qlin);
    gemm_bias<float, ushort><<<dim3(8, 1024), 256, 0, stream>>>(k, Wk, bk, Klin);
    gemm_bias<float, ushort><<<dim3(8, 1024), 256, 0, stream>>>(v, Wv, bv, Vlin);
    attn_kernel<<<dim3(4096), dim3(512), 0, stream>>>(Qlin, Klin, Vlin, Aws);
    gemm_bias<ushort, float><<<dim3(8, 32), 256, 0, stream>>>(Aws, Wo, bo, out);
  }
}